// Round 5
// baseline (617.069 us; speedup 1.0000x reference)
//
#include <hip/hip_runtime.h>
#include <hip/hip_bf16.h>

#define NV 1000000
#define CI 32
#define CO 64
#define KK 9
#define NG (NV / 16)          // 62500 voxel-groups of 16 (exact)
#define EPSV 1e-5f

typedef __bf16 bf16x8 __attribute__((ext_vector_type(8)));
typedef float  f32x4  __attribute__((ext_vector_type(4)));

__device__ __forceinline__ f32x4 mfma16(bf16x8 a, bf16x8 b, f32x4 c) {
    // D[16x16] = A[16x32] * B[32x16] + C
    // A: row=lane&15, k=(lane>>4)*8+j ; B: col=lane&15, k=(lane>>4)*8+j
    // D: col=lane&15, row=(lane>>4)*4+reg   [learn_hip m89 verified]
    return __builtin_amdgcn_mfma_f32_16x16x32_bf16(a, b, c, 0, 0, 0);
}

__device__ __forceinline__ float xredseg(float v) {
    v += __shfl_xor(v, 16, 64);
    v += __shfl_xor(v, 32, 64);
    return v;
}

// ---------------- prep: transpose weights to [k][co][ci] bf16 ----------------
__global__ void k_prep_w(const float* __restrict__ W1, const float* __restrict__ W2,
                         const float* __restrict__ Wd,
                         __bf16* __restrict__ W1T, __bf16* __restrict__ W2T,
                         __bf16* __restrict__ WdT) {
    int i = blockIdx.x * blockDim.x + threadIdx.x;
    const int n1 = KK * CO * CI;      // 18432
    const int n2 = KK * CO * CO;      // 36864
    const int nd = CO * CI;           // 2048
    if (i < n1) {
        int k = i / (CO * CI), r = i % (CO * CI), co = r / CI, ci = r % CI;
        W1T[i] = (__bf16)W1[(k * CI + ci) * CO + co];
    } else if (i < n1 + n2) {
        int j = i - n1;
        int k = j / (CO * CO), r = j % (CO * CO), co = r / CO, ci = r % CO;
        W2T[j] = (__bf16)W2[(k * CO + ci) * CO + co];
    } else if (i < n1 + n2 + nd) {
        int j = i - n1 - n2;
        int co = j / CI, ci = j % CI;
        WdT[j] = (__bf16)Wd[ci * CO + co];
    }
}

// ---------------- prep: x fp32 -> bf16 ----------------
__global__ void k_prep_x(const float* __restrict__ x, __bf16* __restrict__ xb) {
    int i = blockIdx.x * blockDim.x + threadIdx.x;   // one thread per 8 elems
    const float4* px = (const float4*)x + 2 * (size_t)i;
    float4 u = px[0], v = px[1];
    bf16x8 o;
    o[0] = (__bf16)u.x; o[1] = (__bf16)u.y; o[2] = (__bf16)u.z; o[3] = (__bf16)u.w;
    o[4] = (__bf16)v.x; o[5] = (__bf16)v.y; o[6] = (__bf16)v.z; o[7] = (__bf16)v.w;
    *((bf16x8*)xb + i) = o;
}

// ---------------- conv1: register-double-buffered gather-MFMA, W1 in LDS ----------------
// Unchanged from round 4 except grid 768 -> 1024 (4 blocks/CU): A/B test of the
// ~40G transactions/s fabric ceiling theory. If ceiling-bound, no change.
__global__ __launch_bounds__(256, 2) void k_conv1(
    const __bf16* __restrict__ xb, const int* __restrict__ nbr,
    const __bf16* __restrict__ W1T, const __bf16* __restrict__ WdT,
    __bf16* __restrict__ y1b, float* __restrict__ stats) {
    __shared__ __align__(16) char w1smem[KK * CO * CI * 2];   // 36864 B

    const int lane = threadIdx.x & 63;
    const int w    = threadIdx.x >> 6;
    const int r    = lane & 15;
    const int seg  = lane >> 4;

    // stage W1T -> LDS, linear copy: 2304 16B-chunks, 256 threads x 9
#pragma unroll
    for (int j = 0; j < 9; j++) {
        const __bf16* srcp = W1T + (size_t)(j * 256 + threadIdx.x) * 8;
        __builtin_amdgcn_global_load_lds(
            (const __attribute__((address_space(1))) void*)srcp,
            (__attribute__((address_space(3))) void*)(w1smem + j * 4096 + w * 1024),
            16, 0, 0);
    }
    __syncthreads();

    bf16x8 wd[4];
#pragma unroll
    for (int t = 0; t < 4; t++)
        wd[t] = *(const bf16x8*)(WdT + (size_t)(t * 16 + r) * CI + seg * 8);

    float ps1[4] = {0.f,0.f,0.f,0.f}, pq1[4] = {0.f,0.f,0.f,0.f};
    float psd[4] = {0.f,0.f,0.f,0.f}, pqd[4] = {0.f,0.f,0.f,0.f};

    const int slot   = blockIdx.x * 4 + w;
    const int stride = gridDim.x * 4;
    const f32x4 z = {0.f, 0.f, 0.f, 0.f};

    auto loadIdx = [&](int (&idx)[KK], int tile) {
        const int* nb = nbr + (size_t)(tile * 16 + r) * KK;
#pragma unroll
        for (int k = 0; k < KK; k++) idx[k] = nb[k];
    };
    auto gather9 = [&](bf16x8 (&g)[KK], const int (&idx)[KK]) {
#pragma unroll
        for (int k = 0; k < KK; k++)
            g[k] = *(const bf16x8*)(xb + (size_t)idx[k] * CI + seg * 8);
    };
    auto loadAd = [&](int tile) {
        return *(const bf16x8*)(xb + (size_t)(tile * 16 + r) * CI + seg * 8);
    };
    auto compute = [&](int tile, const bf16x8 (&g)[KK], bf16x8 ad) {
        int w1off = 0;
        asm volatile("" : "+v"(w1off));        // defeat cross-iteration hoisting
        const __bf16* wb = (const __bf16*)w1smem + w1off;

        f32x4 acc[4]  = {z, z, z, z};
        f32x4 accd[4] = {z, z, z, z};
#pragma unroll
        for (int t = 0; t < 4; t++) accd[t] = mfma16(ad, wd[t], accd[t]);
#pragma unroll
        for (int k = 0; k < KK; k++) {
#pragma unroll
            for (int t = 0; t < 4; t++) {
                bf16x8 b = *(const bf16x8*)(wb + k * 2048 + t * 512 + r * 32 + seg * 8);
                acc[t] = mfma16(g[k], b, acc[t]);
            }
        }

        const int vb = tile * 16;
#pragma unroll
        for (int t = 0; t < 4; t++) {
#pragma unroll
            for (int rr = 0; rr < 4; rr++) {
                float val = acc[t][rr];
                int row = vb + seg * 4 + rr;
                __builtin_nontemporal_store((__bf16)val, &y1b[(size_t)row * CO + t * 16 + r]);
                ps1[t] += val; pq1[t] += val * val;
                float dv = accd[t][rr];
                psd[t] += dv; pqd[t] += dv * dv;
            }
        }
    };

    int idx0[KK], idx1[KK];
    bf16x8 g0[KK], g1[KK];
    bf16x8 ad0, ad1;

    int it = slot;                    // slot < 4096 <= NG always
    loadIdx(idx0, it);
    gather9(g0, idx0); ad0 = loadAd(it);
    int itn = it + stride;
    bool have = (itn < NG);
    if (have) loadIdx(idx1, itn);

    while (true) {
        // phase A: compute(it, g0); prefetch tile itn into g1, idx for itn+stride
        if (have) {
            gather9(g1, idx1); ad1 = loadAd(itn);
            int it2 = itn + stride;
            if (it2 < NG) loadIdx(idx0, it2);
        }
        compute(it, g0, ad0);
        if (!have) break;
        it = itn; itn = it + stride; have = (itn < NG);

        // phase B: roles swapped
        if (have) {
            gather9(g0, idx0); ad0 = loadAd(itn);
            int it2 = itn + stride;
            if (it2 < NG) loadIdx(idx1, it2);
        }
        compute(it, g1, ad1);
        if (!have) break;
        it = itn; itn = it + stride; have = (itn < NG);
    }

#pragma unroll
    for (int t = 0; t < 4; t++) {
        ps1[t] = xredseg(ps1[t]); pq1[t] = xredseg(pq1[t]);
        psd[t] = xredseg(psd[t]); pqd[t] = xredseg(pqd[t]);
    }
    if (lane < 16) {
#pragma unroll
        for (int t = 0; t < 4; t++) {
            atomicAdd(&stats[0 * 64 + t * 16 + lane], ps1[t]);
            atomicAdd(&stats[1 * 64 + t * 16 + lane], pq1[t]);
            atomicAdd(&stats[2 * 64 + t * 16 + lane], psd[t]);
            atomicAdd(&stats[3 * 64 + t * 16 + lane], pqd[t]);
        }
    }
}

// ---------------- conv2: reg-staged gather, BN1+ReLU applied ONCE at staging ----------------
// Staging is global->reg->transform->ds_write (T14 style). Each staged element
// gets BN+ReLU exactly once per block (72 elems/thread) instead of once per
// wave in the compute loop (144 elems/lane x 2 waves) -> ~4x less BN VALU
// device-wide. Staging thread's channel chunk p = lane&7 is STATIC, so its 8
// BN scale/shift consts live in registers. The XOR part-swizzle moves to the
// ds_write address (per-lane scatter is legal for ds_write, unlike
// global_load_lds). Compute phase is pure ds_read+MFMA.
#define TILE_B (16 * KK * 128)     // 18432 B per buffer

__global__ __launch_bounds__(128, 2) void k_conv2(
    const __bf16* __restrict__ h1b, const int* __restrict__ nbr,
    const __bf16* __restrict__ W2T, const float* __restrict__ g1,
    const float* __restrict__ b1,
    float* __restrict__ y2, float* __restrict__ stats) {
    __shared__ __align__(16) char smem[2][TILE_B];   // 36864 B -> 4 blocks/CU

    const int lane = threadIdx.x & 63;
    const int w    = threadIdx.x >> 6;      // 0..1 = co-half
    const int r    = lane & 15;
    const int seg  = lane >> 4;
    const int p    = lane & 7;              // staging channel-chunk (static)

    bf16x8 w2[KK][2][2];                    // [k][t2][s]
#pragma unroll
    for (int k = 0; k < KK; k++)
#pragma unroll
        for (int t2 = 0; t2 < 2; t2++)
#pragma unroll
            for (int s = 0; s < 2; s++) {
                int co = w * 32 + t2 * 16 + r;
                int ci = s * 32 + seg * 8;
                w2[k][t2][s] = *(const bf16x8*)(W2T + ((size_t)(k * CO + co)) * CO + ci);
            }

    // BN1 consts for this thread's staging channels ci = p*8 .. p*8+7
    float scP[8], shP[8];
#pragma unroll
    for (int j = 0; j < 8; j++) {
        int c0 = p * 8 + j;
        float mu  = stats[c0] * (1.0f / NV);
        float var = stats[64 + c0] * (1.0f / NV) - mu * mu;
        float s   = g1[c0] * rsqrtf(var + EPSV);
        scP[j] = s; shP[j] = b1[c0] - mu * s;
    }

    // per-thread chunk constants: chunk c = w*576 + s*64 + lane
    // ruleIdx = c>>3 (= voxel i*9 + k), LDS dest slot = p ^ (i&7)
    int ri[9], dstoff[9];
#pragma unroll
    for (int s = 0; s < 9; s++) {
        int c = w * 576 + s * 64 + lane;
        int rIdx = c >> 3;
        int i = (rIdx * 57) >> 9;             // floor(rIdx/9), rIdx<512
        ri[s] = rIdx;
        dstoff[s] = rIdx * 128 + ((p ^ (i & 7)) * 16);
    }

    auto loadIdx = [&](int (&ix)[9], int tile) {
        const int* nb = nbr + (size_t)tile * (16 * KK);
#pragma unroll
        for (int s = 0; s < 9; s++) ix[s] = nb[ri[s]];
    };
    auto loadDat = [&](f32x4 (&d)[9], const int (&ix)[9]) {
#pragma unroll
        for (int s = 0; s < 9; s++)
            d[s] = *(const f32x4*)(h1b + (size_t)ix[s] * CO + p * 8);
    };
    auto xform = [&](char* tb, const f32x4 (&d)[9]) {
#pragma unroll
        for (int s = 0; s < 9; s++) {
            union { f32x4 f; bf16x8 b; } u; u.f = d[s];
            bf16x8 o;
#pragma unroll
            for (int j = 0; j < 8; j++)
                o[j] = (__bf16)fmaxf((float)u.b[j] * scP[j] + shP[j], 0.f);
            *(bf16x8*)(tb + dstoff[s]) = o;
        }
    };

    float ps[2] = {0.f, 0.f}, pq[2] = {0.f, 0.f};
    const f32x4 z = {0.f, 0.f, 0.f, 0.f};
    const int sw = r & 7;
    const int G = gridDim.x;

    // pipeline: at loop top, dat = data(it+G) in flight, idxN = idx(it+2G) in flight
    int idxN[9]; f32x4 dat[9];
    int it = blockIdx.x;
    loadIdx(idxN, it);
    loadDat(dat, idxN);                                   // data(it)
    { int t1 = it + G;     loadIdx(idxN, t1 < NG ? t1 : NG - 1); }
    xform(smem[0], dat);                                  // waits data(it)
    loadDat(dat, idxN);                                   // data(it+G)
    { int t2 = it + 2 * G; loadIdx(idxN, t2 < NG ? t2 : NG - 1); }
    __syncthreads();
    int cur = 0;

    for (; it < NG; it += G) {
        // ---- compute tile `it` from smem[cur]: pure ds_read + MFMA ----
        const __bf16* base = (const __bf16*)smem[cur];
        f32x4 acc[2] = {z, z};
#pragma unroll
        for (int k = 0; k < KK; k++) {
            const __bf16* rp = base + (size_t)(r * KK + k) * 64;
            bf16x8 a0 = *(const bf16x8*)(rp + ((seg ^ sw) * 8));
            bf16x8 a1 = *(const bf16x8*)(rp + (((4 + seg) ^ sw) * 8));
            acc[0] = mfma16(a0, w2[k][0][0], acc[0]);
            acc[0] = mfma16(a1, w2[k][0][1], acc[0]);
            acc[1] = mfma16(a0, w2[k][1][0], acc[1]);
            acc[1] = mfma16(a1, w2[k][1][1], acc[1]);
        }

        const int vb = it * 16;
#pragma unroll
        for (int t2 = 0; t2 < 2; t2++) {
#pragma unroll
            for (int rr = 0; rr < 4; rr++) {
                float val = acc[t2][rr];
                int row = vb + seg * 4 + rr;
                int c = w * 32 + t2 * 16 + r;
                __builtin_nontemporal_store(val, &y2[(size_t)row * CO + c]);
                ps[t2] += val; pq[t2] += val * val;
            }
        }

        int nx = it + G;
        if (nx < NG) {
            xform(smem[cur ^ 1], dat);                    // stage tile nx (post-BN)
            loadDat(dat, idxN);                           // issue data(it+2G)
            { int t3 = it + 3 * G; loadIdx(idxN, t3 < NG ? t3 : NG - 1); }
            __syncthreads();                              // writes visible for next compute
            cur ^= 1;
        }
    }

#pragma unroll
    for (int t2 = 0; t2 < 2; t2++) { ps[t2] = xredseg(ps[t2]); pq[t2] = xredseg(pq[t2]); }
    if (lane < 16) {
#pragma unroll
        for (int t2 = 0; t2 < 2; t2++) {
            atomicAdd(&stats[4 * 64 + w * 32 + t2 * 16 + lane], ps[t2]);
            atomicAdd(&stats[5 * 64 + w * 32 + t2 * 16 + lane], pq[t2]);
        }
    }
}

// ---------------- final: out = relu(BN2(y2) + BNd(xb@WdT)), in place on d_out ----------------
__global__ __launch_bounds__(256, 2) void k_final(
    const __bf16* __restrict__ xb, const __bf16* __restrict__ WdT,
    float* __restrict__ out, const float* __restrict__ stats,
    const float* __restrict__ g2, const float* __restrict__ b2,
    const float* __restrict__ gd, const float* __restrict__ bd) {
    __shared__ float s2[CO], sh2[CO], sdv[CO], shd[CO];
    int t = threadIdx.x;
    if (t < CO) {
        float mu2  = stats[4 * 64 + t] * (1.0f / NV);
        float var2 = stats[5 * 64 + t] * (1.0f / NV) - mu2 * mu2;
        float s = g2[t] * rsqrtf(var2 + EPSV);
        s2[t] = s; sh2[t] = b2[t] - mu2 * s;
        float mud  = stats[2 * 64 + t] * (1.0f / NV);
        float vard = stats[3 * 64 + t] * (1.0f / NV) - mud * mud;
        float sd = gd[t] * rsqrtf(vard + EPSV);
        sdv[t] = sd; shd[t] = bd[t] - mud * sd;
    }
    __syncthreads();

    const int lane = threadIdx.x & 63;
    const int w    = threadIdx.x >> 6;
    const int r    = lane & 15;
    const int seg  = lane >> 4;

    bf16x8 wd[4];
#pragma unroll
    for (int t4 = 0; t4 < 4; t4++)
        wd[t4] = *(const bf16x8*)(WdT + (size_t)(t4 * 16 + r) * CI + seg * 8);

    const int slot = blockIdx.x * 4 + w;
    const int nslots = gridDim.x * 4;
    const f32x4 z = {0.f, 0.f, 0.f, 0.f};

    for (int gid = slot; gid < NG; gid += nslots) {
        const int vb = gid * 16;
        const int v  = vb + r;
        bf16x8 ad = *(const bf16x8*)(xb + (size_t)v * CI + seg * 8);
        f32x4 accd[4] = {z, z, z, z};
#pragma unroll
        for (int t4 = 0; t4 < 4; t4++) accd[t4] = mfma16(ad, wd[t4], accd[t4]);
#pragma unroll
        for (int t4 = 0; t4 < 4; t4++) {
#pragma unroll
            for (int rr = 0; rr < 4; rr++) {
                int row = vb + seg * 4 + rr;
                int c = t4 * 16 + r;
                size_t o = (size_t)row * CO + c;
                float y2v = out[o];
                float res = s2[c] * y2v + sh2[c] + sdv[c] * accd[t4][rr] + shd[c];
                out[o] = fmaxf(res, 0.f);
            }
        }
    }
}

extern "C" void kernel_launch(void* const* d_in, const int* in_sizes, int n_in,
                              void* d_out, int out_size, void* d_ws, size_t ws_size,
                              hipStream_t stream) {
    const float* x  = (const float*)d_in[0];
    const float* W1 = (const float*)d_in[1];
    const float* g1 = (const float*)d_in[2];
    const float* b1 = (const float*)d_in[3];
    const float* W2 = (const float*)d_in[4];
    const float* g2 = (const float*)d_in[5];
    const float* b2 = (const float*)d_in[6];
    const float* Wd = (const float*)d_in[7];
    const float* gd = (const float*)d_in[8];
    const float* bd = (const float*)d_in[9];
    const int*  nbr = (const int*)d_in[10];

    char* ws = (char*)d_ws;
    __bf16* xb  = (__bf16*)ws;                              // 64,000,000 B
    __bf16* y1b = (__bf16*)(ws + 64000000);                 // 128,000,000 B
    __bf16* W1T = (__bf16*)(ws + 192000000);                // 36,864 B
    __bf16* W2T = W1T + KK * CO * CI;                       // 73,728 B
    __bf16* WdT = W2T + KK * CO * CO;                       // 4,096 B
    float* stats = (float*)(ws + 192000000 + 2 * (KK*CO*CI + KK*CO*CO + CO*CI));

    hipMemsetAsync(stats, 0, 6 * 64 * sizeof(float), stream);

    int nprep = KK*CO*CI + KK*CO*CO + CO*CI;                // 57344
    k_prep_w<<<(nprep + 255) / 256, 256, 0, stream>>>(W1, W2, Wd, W1T, W2T, WdT);
    k_prep_x<<<(NV * CI / 8) / 256, 256, 0, stream>>>(x, xb);   // 15625 blocks
    k_conv1<<<1024, 256, 0, stream>>>(xb, nbr, W1T, WdT, y1b, stats);
    k_conv2<<<1024, 128, 0, stream>>>(y1b, nbr, W2T, g1, b1, (float*)d_out, stats);
    k_final<<<1024, 256, 0, stream>>>(xb, WdT, (float*)d_out, stats, g2, b2, gd, bd);
}